// Round 1
// baseline (2782.965 us; speedup 1.0000x reference)
//
#include <hip/hip_runtime.h>
#include <hip/hip_bf16.h>

#define N_NODES 50000
#define N_EDGES 800000
#define CH 128
#define OUT_CH 64
#define K_ORD 25

// ---------- helpers ----------
static __device__ __forceinline__ unsigned short f2bf(float x) {
    union { float f; unsigned int u; } v; v.f = x;
    unsigned int r = v.u + 0x7FFFu + ((v.u >> 16) & 1u);
    return (unsigned short)(r >> 16);
}

typedef __attribute__((ext_vector_type(8))) short s16x8;
typedef __attribute__((ext_vector_type(4))) float f32x4;

// ---------- CSR build ----------
__global__ void count_kernel(const int* __restrict__ ei, float* __restrict__ deg,
                             int* __restrict__ indeg, int E) {
    int e = blockIdx.x * blockDim.x + threadIdx.x;
    if (e >= E) return;
    int s = ei[e];
    int d = ei[E + e];
    atomicAdd(&deg[s], 1.0f);
    atomicAdd(&indeg[d], 1);
}

__global__ void scan_kernel(const int* __restrict__ indeg, int* __restrict__ rowptr,
                            int* __restrict__ cursor, int n) {
    __shared__ int tmp[1024];
    int tid = threadIdx.x;
    int chunk = (n + 1023) >> 10;
    int s0 = tid * chunk;
    int s1 = min(s0 + chunk, n);
    int s = 0;
    for (int i = s0; i < s1; ++i) s += indeg[i];
    tmp[tid] = s;
    __syncthreads();
    for (int off = 1; off < 1024; off <<= 1) {
        int v = 0;
        if (tid >= off) v = tmp[tid - off];
        __syncthreads();
        if (tid >= off) tmp[tid] += v;
        __syncthreads();
    }
    int base = tmp[tid] - s;   // exclusive prefix
    for (int i = s0; i < s1; ++i) {
        rowptr[i] = base;
        cursor[i] = base;
        base += indeg[i];
    }
    if (tid == 1023) rowptr[n] = tmp[1023];
}

__global__ void scatter_kernel(const int* __restrict__ ei, const float* __restrict__ deg,
                               int* __restrict__ cursor, int* __restrict__ col,
                               float* __restrict__ ew, int E) {
    int e = blockIdx.x * blockDim.x + threadIdx.x;
    if (e >= E) return;
    int s = ei[e];
    int d = ei[E + e];
    float ds = deg[s], dd = deg[d];
    float dis_s = ds > 0.f ? rsqrtf(ds) : 0.f;
    float dis_d = dd > 0.f ? rsqrtf(dd) : 0.f;
    int pos = atomicAdd(&cursor[d], 1);
    col[pos] = s;
    ew[pos] = -dis_s * dis_d;
}

// ---------- prop: tout = (mode ? 2*prop(tin) - tprev : prop(tin)) ----------
// one wave per node; lane handles channels 2*lane, 2*lane+1
__global__ __launch_bounds__(256) void prop_kernel(
    const float* __restrict__ tin, const float* __restrict__ tprev,
    float* __restrict__ tout, const int* __restrict__ rowptr,
    const int* __restrict__ col, const float* __restrict__ ew, int n, int mode) {
    int wid = blockIdx.x * 4 + (threadIdx.x >> 6);
    if (wid >= n) return;
    int lane = threadIdx.x & 63;
    int beg = rowptr[wid], end = rowptr[wid + 1];
    const float2* tin2 = (const float2*)tin;
    float2 acc = make_float2(0.f, 0.f);
    for (int e0 = beg; e0 < end; e0 += 64) {
        int ne = min(64, end - e0);
        int c = 0; float w = 0.f;
        if (lane < ne) { c = col[e0 + lane]; w = ew[e0 + lane]; }
        for (int j = 0; j < ne; ++j) {
            int   cj = __shfl(c, j);
            float wj = __shfl(w, j);
            float2 v = tin2[cj * 64 + lane];
            acc.x = fmaf(wj, v.x, acc.x);
            acc.y = fmaf(wj, v.y, acc.y);
        }
    }
    float2 o;
    if (mode) {
        float2 p = ((const float2*)tprev)[wid * 64 + lane];
        o = make_float2(2.f * acc.x - p.x, 2.f * acc.y - p.y);
    } else {
        o = acc;
    }
    ((float2*)tout)[wid * 64 + lane] = o;
}

// ---------- GEMM: C[M,128] (+)= A[M,128] @ W[128,128], bf16 MFMA ----------
// block 256 (4 waves), tile BM=128 rows; each wave: 32 rows x 128 cols
__global__ __launch_bounds__(256) void gemm_kernel(
    const float* __restrict__ A, const float* __restrict__ W,
    float* __restrict__ C, int M, int beta) {
    __shared__ unsigned short As[128 * 128]; // swizzled, 16B-granule XOR (r&15)
    __shared__ unsigned short Ws[128 * 128]; // [n][k], swizzled by (n&15)
    int tid = threadIdx.x;
    int row0 = blockIdx.x * 128;

    // stage A (fp32 -> bf16), 4096 float4 loads
    for (int i = 0; i < 16; ++i) {
        int idx = tid + i * 256;
        int r = idx >> 5;
        int c4 = idx & 31;          // float4 index within row
        float4 v = make_float4(0.f, 0.f, 0.f, 0.f);
        int gr = row0 + r;
        if (gr < M) v = ((const float4*)A)[gr * 32 + c4];
        int g = c4 >> 1;            // 16B granule (8 bf16)
        int h = c4 & 1;
        int gs = g ^ (r & 15);
        unsigned long long pk =
            (unsigned long long)f2bf(v.x) |
            ((unsigned long long)f2bf(v.y) << 16) |
            ((unsigned long long)f2bf(v.z) << 32) |
            ((unsigned long long)f2bf(v.w) << 48);
        *(unsigned long long*)(&As[r * 128 + gs * 8 + h * 4]) = pk;
    }
    // stage W transposed: Ws[n][k] = W[k][n]
    for (int i = 0; i < 16; ++i) {
        int idx = tid + i * 256;
        int k = idx >> 5;
        int n4 = idx & 31;
        float4 v = ((const float4*)W)[k * 32 + n4];
        int g = k >> 3;
        int kk = k & 7;
        float vv[4] = { v.x, v.y, v.z, v.w };
        for (int j = 0; j < 4; ++j) {
            int nn = n4 * 4 + j;
            int gs = g ^ (nn & 15);
            Ws[nn * 128 + gs * 8 + kk] = f2bf(vv[j]);
        }
    }
    __syncthreads();

    int wave = tid >> 6, lane = tid & 63;
    int wrow = wave * 32;
    int lr = lane & 15, kg = lane >> 4;
    f32x4 acc[2][8];
    for (int a = 0; a < 2; ++a)
        for (int c = 0; c < 8; ++c)
            acc[a][c] = (f32x4){0.f, 0.f, 0.f, 0.f};

    for (int kc = 0; kc < 4; ++kc) {
        int gbase = kc * 4 + kg;
        int gs = gbase ^ lr;
        s16x8 a0 = *(const s16x8*)(&As[(wrow + lr) * 128 + gs * 8]);
        s16x8 a1 = *(const s16x8*)(&As[(wrow + 16 + lr) * 128 + gs * 8]);
        for (int c = 0; c < 8; ++c) {
            s16x8 bfr = *(const s16x8*)(&Ws[(c * 16 + lr) * 128 + gs * 8]);
            acc[0][c] = __builtin_amdgcn_mfma_f32_16x16x32_bf16(a0, bfr, acc[0][c], 0, 0, 0);
            acc[1][c] = __builtin_amdgcn_mfma_f32_16x16x32_bf16(a1, bfr, acc[1][c], 0, 0, 0);
        }
    }
    // write back: C row = (lane>>4)*4 + j, col = c*16 + (lane&15)
    for (int rf = 0; rf < 2; ++rf)
        for (int c = 0; c < 8; ++c)
            for (int j = 0; j < 4; ++j) {
                int gr = row0 + wrow + rf * 16 + kg * 4 + j;
                int gc = c * 16 + lr;
                if (gr < M) {
                    float v = acc[rf][c][j];
                    if (beta) v += C[gr * 128 + gc];
                    C[gr * 128 + gc] = v;
                }
            }
}

// ---------- head: h=leaky(acc+b); mu=h@w_mu+b_mu; ls=h@w_ls+b_ls; normalize ----------
__global__ __launch_bounds__(256) void head_kernel(
    const float* __restrict__ acc, const float* __restrict__ b,
    const float* __restrict__ w_mu, const float* __restrict__ b_mu,
    const float* __restrict__ w_ls, const float* __restrict__ b_ls,
    float* __restrict__ out, int n) {
    int node = blockIdx.x * 4 + (threadIdx.x >> 6);
    if (node >= n) return;
    int o = threadIdx.x & 63;
    const float* arow = acc + (size_t)node * CH;
    float mu = 0.f, ls = 0.f;
    for (int c = 0; c < CH; ++c) {
        float h = arow[c] + b[c];
        h = h > 0.f ? h : 0.01f * h;
        mu = fmaf(h, w_mu[c * OUT_CH + o], mu);
        ls = fmaf(h, w_ls[c * OUT_CH + o], ls);
    }
    mu += b_mu[o];
    ls += b_ls[o];
    float s2 = ls * ls;
    for (int off = 32; off; off >>= 1) s2 += __shfl_xor(s2, off);
    float scale = 1.8f / fmaxf(sqrtf(s2), 1e-12f);
    int base = node * OUT_CH + o;
    out[base] = mu;                               // mu
    out[N_NODES * OUT_CH + base] = ls * scale;    // logstd
    out[2 * N_NODES * OUT_CH + base] = mu;        // zeta
}

// ---------- host ----------
extern "C" void kernel_launch(void* const* d_in, const int* in_sizes, int n_in,
                              void* d_out, int out_size, void* d_ws, size_t ws_size,
                              hipStream_t stream) {
    const float* x    = (const float*)d_in[0];
    const int*   ei   = (const int*)d_in[1];
    const float* W    = (const float*)d_in[2];
    const float* b    = (const float*)d_in[3];
    const float* w_mu = (const float*)d_in[4];
    const float* b_mu = (const float*)d_in[5];
    const float* w_ls = (const float*)d_in[6];
    const float* b_ls = (const float*)d_in[7];

    const int N = N_NODES, E = N_EDGES;
    char* p = (char*)d_ws;
    auto alloc = [&](size_t bytes) {
        char* r = p;
        p += (bytes + 511) & ~(size_t)511;
        return r;
    };
    float* deg    = (float*)alloc((size_t)N * 4);
    int*   indeg  = (int*)alloc((size_t)N * 4);
    int*   rowptr = (int*)alloc((size_t)(N + 1) * 4);
    int*   cursor = (int*)alloc((size_t)N * 4);
    int*   col    = (int*)alloc((size_t)E * 4);
    float* ew     = (float*)alloc((size_t)E * 4);
    float* bufA   = (float*)alloc((size_t)N * CH * 4);
    float* bufB   = (float*)alloc((size_t)N * CH * 4);
    float* accbuf = (float*)alloc((size_t)N * CH * 4);

    hipMemsetAsync(deg, 0, (size_t)N * 4, stream);
    hipMemsetAsync(indeg, 0, (size_t)N * 4, stream);

    count_kernel<<<(E + 255) / 256, 256, 0, stream>>>(ei, deg, indeg, E);
    scan_kernel<<<1, 1024, 0, stream>>>(indeg, rowptr, cursor, N);
    scatter_kernel<<<(E + 255) / 256, 256, 0, stream>>>(ei, deg, cursor, col, ew, E);

    int gemm_grid = (N + 127) / 128;
    int prop_grid = (N + 3) / 4;

    // out0 = x @ W0
    gemm_kernel<<<gemm_grid, 256, 0, stream>>>(x, W, accbuf, N, 0);
    // t1 = prop(x)
    prop_kernel<<<prop_grid, 256, 0, stream>>>(x, x, bufA, rowptr, col, ew, N, 0);
    // out += t1 @ W1
    gemm_kernel<<<gemm_grid, 256, 0, stream>>>(bufA, W + CH * CH, accbuf, N, 1);

    const float* tm2 = x;
    float* tm1 = bufA;
    for (int k = 2; k < K_ORD; ++k) {
        float* tout = (k == 2) ? bufB : (float*)tm2;
        prop_kernel<<<prop_grid, 256, 0, stream>>>(tm1, tm2, tout, rowptr, col, ew, N, 1);
        gemm_kernel<<<gemm_grid, 256, 0, stream>>>(tout, W + (size_t)k * CH * CH, accbuf, N, 1);
        tm2 = tm1;
        tm1 = tout;
    }

    head_kernel<<<(N + 3) / 4, 256, 0, stream>>>(accbuf, b, w_mu, b_mu, w_ls, b_ls,
                                                 (float*)d_out, N);
}

// Round 2
// 1880.963 us; speedup vs baseline: 1.4795x; 1.4795x over previous
//
#include <hip/hip_runtime.h>
#include <hip/hip_fp16.h>

#define N_NODES 50000
#define N_EDGES 800000
#define CH 128
#define OUT_CH 64
#define K_ORD 25

typedef __attribute__((ext_vector_type(8))) short s16x8;
typedef __attribute__((ext_vector_type(4))) float f32x4;

union U4H8 { uint4 u; __half2 h2[4]; ushort us[8]; };

// ---------- CSR build ----------
__global__ void count_kernel(const int* __restrict__ ei, float* __restrict__ deg,
                             int* __restrict__ indeg, int E) {
    int e = blockIdx.x * blockDim.x + threadIdx.x;
    if (e >= E) return;
    int s = ei[e];
    int d = ei[E + e];
    atomicAdd(&deg[s], 1.0f);
    atomicAdd(&indeg[d], 1);
}

__global__ void scan_kernel(const int* __restrict__ indeg, int* __restrict__ rowptr,
                            int* __restrict__ cursor, int n) {
    __shared__ int tmp[1024];
    int tid = threadIdx.x;
    int chunk = (n + 1023) >> 10;
    int s0 = tid * chunk;
    int s1 = min(s0 + chunk, n);
    int s = 0;
    for (int i = s0; i < s1; ++i) s += indeg[i];
    tmp[tid] = s;
    __syncthreads();
    for (int off = 1; off < 1024; off <<= 1) {
        int v = 0;
        if (tid >= off) v = tmp[tid - off];
        __syncthreads();
        if (tid >= off) tmp[tid] += v;
        __syncthreads();
    }
    int base = tmp[tid] - s;   // exclusive prefix
    for (int i = s0; i < s1; ++i) {
        rowptr[i] = base;
        cursor[i] = base;
        base += indeg[i];
    }
    if (tid == 1023) rowptr[n] = tmp[1023];
}

__global__ void scatter_kernel(const int* __restrict__ ei, const float* __restrict__ deg,
                               int* __restrict__ cursor, int* __restrict__ col,
                               float* __restrict__ ew, int E) {
    int e = blockIdx.x * blockDim.x + threadIdx.x;
    if (e >= E) return;
    int s = ei[e];
    int d = ei[E + e];
    float ds = deg[s], dd = deg[d];
    float dis_s = ds > 0.f ? rsqrtf(ds) : 0.f;
    float dis_d = dd > 0.f ? rsqrtf(dd) : 0.f;
    int pos = atomicAdd(&cursor[d], 1);
    col[pos] = s;
    ew[pos] = -dis_s * dis_d;
}

// ---------- fp32 -> fp16 convert (for x) ----------
__global__ __launch_bounds__(256) void cvt_kernel(const float* __restrict__ in,
                                                  ushort* __restrict__ out, int n8) {
    int i = blockIdx.x * 256 + threadIdx.x;
    if (i >= n8) return;
    float4 a = ((const float4*)in)[2 * i];
    float4 b = ((const float4*)in)[2 * i + 1];
    U4H8 p;
    p.h2[0] = __float22half2_rn(make_float2(a.x, a.y));
    p.h2[1] = __float22half2_rn(make_float2(a.z, a.w));
    p.h2[2] = __float22half2_rn(make_float2(b.x, b.y));
    p.h2[3] = __float22half2_rn(make_float2(b.z, b.w));
    ((uint4*)out)[i] = p.u;
}

// ---------- prop: gather fp16 rows, fp32 recurrence state, write fp32 + fp16 mirror ----------
// one wave per node; 4 groups x 16 lanes, each group handles one edge (16B/lane loads)
__global__ __launch_bounds__(256) void prop_kernel(
    const ushort* __restrict__ tin_h, const float* __restrict__ tprev,
    float* __restrict__ tout, ushort* __restrict__ tout_h,
    const int* __restrict__ rowptr, const int* __restrict__ col,
    const float* __restrict__ ew, int n, int mode) {
    int wid = blockIdx.x * 4 + (threadIdx.x >> 6);
    if (wid >= n) return;
    int lane = threadIdx.x & 63;
    int g = lane >> 4, sub = lane & 15;
    int beg = rowptr[wid], end = rowptr[wid + 1];
    float acc[8] = {0.f, 0.f, 0.f, 0.f, 0.f, 0.f, 0.f, 0.f};
    for (int e0 = beg; e0 < end; e0 += 64) {
        int ne = min(64, end - e0);
        int c = 0; float w = 0.f;
        if (lane < ne) { c = col[e0 + lane]; w = ew[e0 + lane]; }
        for (int j4 = 0; j4 < ne; j4 += 4) {
            int j = j4 + g;
            int cj = __shfl(c, j & 63);
            float wj = __shfl(w, j & 63);
            if (j >= ne) wj = 0.f;   // lanes >= ne hold c=0 -> harmless cached row-0 load x 0
            U4H8 v;
            v.u = ((const uint4*)(tin_h + (size_t)cj * CH))[sub];
            #pragma unroll
            for (int t = 0; t < 4; ++t) {
                float2 f = __half22float2(v.h2[t]);
                acc[2 * t]     = fmaf(wj, f.x, acc[2 * t]);
                acc[2 * t + 1] = fmaf(wj, f.y, acc[2 * t + 1]);
            }
        }
    }
    #pragma unroll
    for (int i = 0; i < 8; ++i) {
        acc[i] += __shfl_xor(acc[i], 16);
        acc[i] += __shfl_xor(acc[i], 32);
    }
    if (g == 0) {
        size_t base = (size_t)wid * CH + sub * 8;
        float r[8];
        if (mode) {
            float4 p0 = *(const float4*)(tprev + base);
            float4 p1 = *(const float4*)(tprev + base + 4);
            r[0] = 2.f * acc[0] - p0.x; r[1] = 2.f * acc[1] - p0.y;
            r[2] = 2.f * acc[2] - p0.z; r[3] = 2.f * acc[3] - p0.w;
            r[4] = 2.f * acc[4] - p1.x; r[5] = 2.f * acc[5] - p1.y;
            r[6] = 2.f * acc[6] - p1.z; r[7] = 2.f * acc[7] - p1.w;
        } else {
            #pragma unroll
            for (int i = 0; i < 8; ++i) r[i] = acc[i];
        }
        *(float4*)(tout + base)     = make_float4(r[0], r[1], r[2], r[3]);
        *(float4*)(tout + base + 4) = make_float4(r[4], r[5], r[6], r[7]);
        U4H8 p;
        p.h2[0] = __float22half2_rn(make_float2(r[0], r[1]));
        p.h2[1] = __float22half2_rn(make_float2(r[2], r[3]));
        p.h2[2] = __float22half2_rn(make_float2(r[4], r[5]));
        p.h2[3] = __float22half2_rn(make_float2(r[6], r[7]));
        *(uint4*)(tout_h + base) = p.u;
    }
}

// ---------- GEMM: C[M,128] (+)= A_h[M,128] @ W[128,128], fp16 MFMA ----------
__global__ __launch_bounds__(256) void gemm_kernel(
    const ushort* __restrict__ A_h, const float* __restrict__ W,
    float* __restrict__ C, int M, int beta) {
    __shared__ ushort As[128 * 128];
    __shared__ ushort Ws[128 * 128];
    int tid = threadIdx.x;
    int row0 = blockIdx.x * 128;

    // stage A (fp16, already converted): 2048 16B granules
    #pragma unroll
    for (int i = 0; i < 8; ++i) {
        int idx = tid + i * 256;
        int r = idx >> 4, gg = idx & 15;
        uint4 v = make_uint4(0u, 0u, 0u, 0u);
        int gr = row0 + r;
        if (gr < M) v = ((const uint4*)(A_h + (size_t)gr * CH))[gg];
        int gs = gg ^ (r & 15);
        *(uint4*)(&As[r * 128 + gs * 8]) = v;
    }
    // stage W transposed fp32->fp16: Ws[n][k] = W[k][n]
    #pragma unroll
    for (int i = 0; i < 16; ++i) {
        int idx = tid + i * 256;
        int k = idx >> 5, n4 = idx & 31;
        float4 v = ((const float4*)W)[k * 32 + n4];
        int gk = k >> 3, kk = k & 7;
        float vv[4] = { v.x, v.y, v.z, v.w };
        #pragma unroll
        for (int j = 0; j < 4; ++j) {
            int nn = n4 * 4 + j;
            int gs = gk ^ (nn & 15);
            Ws[nn * 128 + gs * 8 + kk] = __half_as_ushort(__float2half_rn(vv[j]));
        }
    }
    __syncthreads();

    int wave = tid >> 6, lane = tid & 63;
    int wrow = wave * 32;
    int lr = lane & 15, kg = lane >> 4;
    f32x4 acc[2][8];
    #pragma unroll
    for (int a = 0; a < 2; ++a)
        #pragma unroll
        for (int c = 0; c < 8; ++c)
            acc[a][c] = (f32x4){0.f, 0.f, 0.f, 0.f};

    #pragma unroll
    for (int kc = 0; kc < 4; ++kc) {
        int gbase = kc * 4 + kg;
        int gs = gbase ^ lr;
        s16x8 a0 = *(const s16x8*)(&As[(wrow + lr) * 128 + gs * 8]);
        s16x8 a1 = *(const s16x8*)(&As[(wrow + 16 + lr) * 128 + gs * 8]);
        #pragma unroll
        for (int c = 0; c < 8; ++c) {
            s16x8 bfr = *(const s16x8*)(&Ws[(c * 16 + lr) * 128 + gs * 8]);
            acc[0][c] = __builtin_amdgcn_mfma_f32_16x16x32_f16(a0, bfr, acc[0][c], 0, 0, 0);
            acc[1][c] = __builtin_amdgcn_mfma_f32_16x16x32_f16(a1, bfr, acc[1][c], 0, 0, 0);
        }
    }
    #pragma unroll
    for (int rf = 0; rf < 2; ++rf)
        #pragma unroll
        for (int c = 0; c < 8; ++c)
            #pragma unroll
            for (int j = 0; j < 4; ++j) {
                int gr = row0 + wrow + rf * 16 + kg * 4 + j;
                int gc = c * 16 + lr;
                if (gr < M) {
                    float v = acc[rf][c][j];
                    if (beta) v += C[(size_t)gr * 128 + gc];
                    C[(size_t)gr * 128 + gc] = v;
                }
            }
}

// ---------- head: MFMA over Wcat = [w_mu | w_ls], fused leaky+bias+normalize ----------
__global__ __launch_bounds__(256) void head_kernel(
    const float* __restrict__ acc_in, const float* __restrict__ b,
    const float* __restrict__ w_mu, const float* __restrict__ b_mu,
    const float* __restrict__ w_ls, const float* __restrict__ b_ls,
    float* __restrict__ out, int M) {
    __shared__ ushort Hs[128 * 128];
    __shared__ ushort Ws[128 * 128];
    __shared__ float s_b[128];
    int tid = threadIdx.x;
    int row0 = blockIdx.x * 128;
    if (tid < 128) s_b[tid] = b[tid];
    __syncthreads();

    // stage H = fp16(leaky(acc+b)), swizzled
    #pragma unroll
    for (int i = 0; i < 16; ++i) {
        int idx = tid + i * 256;
        int r = idx >> 5, c4 = idx & 31;
        float4 v = make_float4(0.f, 0.f, 0.f, 0.f);
        int gr = row0 + r;
        if (gr < M) v = ((const float4*)(acc_in + (size_t)gr * CH))[c4];
        float hv[4] = { v.x, v.y, v.z, v.w };
        #pragma unroll
        for (int j = 0; j < 4; ++j) {
            float h = hv[j] + s_b[c4 * 4 + j];
            hv[j] = h > 0.f ? h : 0.01f * h;
        }
        __half2 p0 = __float22half2_rn(make_float2(hv[0], hv[1]));
        __half2 p1 = __float22half2_rn(make_float2(hv[2], hv[3]));
        int gg = c4 >> 1, hh = c4 & 1;
        int gs = gg ^ (r & 15);
        uint2 pk;
        pk.x = *(unsigned int*)&p0;
        pk.y = *(unsigned int*)&p1;
        *(uint2*)(&Hs[r * 128 + gs * 8 + hh * 4]) = pk;
    }
    // stage Wcat[n][k]: n<64 -> w_mu[k*64+n], n>=64 -> w_ls[k*64+(n-64)]
    #pragma unroll
    for (int i = 0; i < 16; ++i) {
        int idx = tid + i * 256;
        int k = idx >> 5, n4 = idx & 31;
        const float* src = (n4 < 16) ? w_mu : w_ls;
        float4 v = ((const float4*)src)[k * 16 + (n4 & 15)];
        int gk = k >> 3, kk = k & 7;
        float vv[4] = { v.x, v.y, v.z, v.w };
        #pragma unroll
        for (int j = 0; j < 4; ++j) {
            int nn = n4 * 4 + j;
            int gs = gk ^ (nn & 15);
            Ws[nn * 128 + gs * 8 + kk] = __half_as_ushort(__float2half_rn(vv[j]));
        }
    }
    __syncthreads();

    int wave = tid >> 6, lane = tid & 63;
    int wrow = wave * 32;
    int lr = lane & 15, kg = lane >> 4;
    f32x4 acc[2][8];
    #pragma unroll
    for (int a = 0; a < 2; ++a)
        #pragma unroll
        for (int c = 0; c < 8; ++c)
            acc[a][c] = (f32x4){0.f, 0.f, 0.f, 0.f};

    #pragma unroll
    for (int kc = 0; kc < 4; ++kc) {
        int gbase = kc * 4 + kg;
        int gs = gbase ^ lr;
        s16x8 a0 = *(const s16x8*)(&Hs[(wrow + lr) * 128 + gs * 8]);
        s16x8 a1 = *(const s16x8*)(&Hs[(wrow + 16 + lr) * 128 + gs * 8]);
        #pragma unroll
        for (int c = 0; c < 8; ++c) {
            s16x8 bfr = *(const s16x8*)(&Ws[(c * 16 + lr) * 128 + gs * 8]);
            acc[0][c] = __builtin_amdgcn_mfma_f32_16x16x32_f16(a0, bfr, acc[0][c], 0, 0, 0);
            acc[1][c] = __builtin_amdgcn_mfma_f32_16x16x32_f16(a1, bfr, acc[1][c], 0, 0, 0);
        }
    }

    // epilogue: cols 0-63 = mu (also zeta), cols 64-127 = ls -> normalize per row
    #pragma unroll
    for (int rf = 0; rf < 2; ++rf)
        #pragma unroll
        for (int j = 0; j < 4; ++j) {
            int gr = row0 + wrow + rf * 16 + kg * 4 + j;
            float muv[4], lsv[4];
            float s2 = 0.f;
            #pragma unroll
            for (int c = 0; c < 4; ++c) {
                muv[c] = acc[rf][c][j] + b_mu[c * 16 + lr];
                float l = acc[rf][4 + c][j] + b_ls[c * 16 + lr];
                lsv[c] = l;
                s2 = fmaf(l, l, s2);
            }
            s2 += __shfl_xor(s2, 1);
            s2 += __shfl_xor(s2, 2);
            s2 += __shfl_xor(s2, 4);
            s2 += __shfl_xor(s2, 8);
            float sc = 1.8f / fmaxf(sqrtf(s2), 1e-12f);
            if (gr < M) {
                size_t base = (size_t)gr * OUT_CH;
                #pragma unroll
                for (int c = 0; c < 4; ++c) {
                    int gc = c * 16 + lr;
                    out[base + gc] = muv[c];
                    out[(size_t)N_NODES * OUT_CH + base + gc] = lsv[c] * sc;
                    out[2 * (size_t)N_NODES * OUT_CH + base + gc] = muv[c];
                }
            }
        }
}

// ---------- host ----------
extern "C" void kernel_launch(void* const* d_in, const int* in_sizes, int n_in,
                              void* d_out, int out_size, void* d_ws, size_t ws_size,
                              hipStream_t stream) {
    const float* x    = (const float*)d_in[0];
    const int*   ei   = (const int*)d_in[1];
    const float* W    = (const float*)d_in[2];
    const float* b    = (const float*)d_in[3];
    const float* w_mu = (const float*)d_in[4];
    const float* b_mu = (const float*)d_in[5];
    const float* w_ls = (const float*)d_in[6];
    const float* b_ls = (const float*)d_in[7];

    const int N = N_NODES, E = N_EDGES;
    char* p = (char*)d_ws;
    auto alloc = [&](size_t bytes) {
        char* r = p;
        p += (bytes + 511) & ~(size_t)511;
        return r;
    };
    float*  deg    = (float*)alloc((size_t)N * 4);
    int*    indeg  = (int*)alloc((size_t)N * 4);
    int*    rowptr = (int*)alloc((size_t)(N + 1) * 4);
    int*    cursor = (int*)alloc((size_t)N * 4);
    int*    col    = (int*)alloc((size_t)E * 4);
    float*  ew     = (float*)alloc((size_t)E * 4);
    float*  bufA   = (float*)alloc((size_t)N * CH * 4);
    float*  bufB   = (float*)alloc((size_t)N * CH * 4);
    float*  accbuf = (float*)alloc((size_t)N * CH * 4);
    ushort* x_h    = (ushort*)alloc((size_t)N * CH * 2);
    ushort* bufA_h = (ushort*)alloc((size_t)N * CH * 2);
    ushort* bufB_h = (ushort*)alloc((size_t)N * CH * 2);

    hipMemsetAsync(deg, 0, (size_t)N * 4, stream);
    hipMemsetAsync(indeg, 0, (size_t)N * 4, stream);

    count_kernel<<<(E + 255) / 256, 256, 0, stream>>>(ei, deg, indeg, E);
    scan_kernel<<<1, 1024, 0, stream>>>(indeg, rowptr, cursor, N);
    scatter_kernel<<<(E + 255) / 256, 256, 0, stream>>>(ei, deg, cursor, col, ew, E);
    cvt_kernel<<<(N * CH / 8 + 255) / 256, 256, 0, stream>>>(x, x_h, N * CH / 8);

    int gemm_grid = (N + 127) / 128;
    int prop_grid = (N + 3) / 4;

    // out0 = x @ W0
    gemm_kernel<<<gemm_grid, 256, 0, stream>>>(x_h, W, accbuf, N, 0);
    // t1 = prop(x)
    prop_kernel<<<prop_grid, 256, 0, stream>>>(x_h, x, bufA, bufA_h, rowptr, col, ew, N, 0);
    // out += t1 @ W1
    gemm_kernel<<<gemm_grid, 256, 0, stream>>>(bufA_h, W + CH * CH, accbuf, N, 1);

    const float* tm2f = x;
    float* tm1f = bufA;
    ushort* tm2h = x_h;
    ushort* tm1h = bufA_h;
    for (int k = 2; k < K_ORD; ++k) {
        float*  toutf = (k == 2) ? bufB : (float*)tm2f;
        ushort* touth = (k == 2) ? bufB_h : tm2h;
        prop_kernel<<<prop_grid, 256, 0, stream>>>(tm1h, tm2f, toutf, touth,
                                                   rowptr, col, ew, N, 1);
        gemm_kernel<<<gemm_grid, 256, 0, stream>>>(touth, W + (size_t)k * CH * CH,
                                                   accbuf, N, 1);
        tm2f = tm1f; tm2h = tm1h;
        tm1f = toutf; tm1h = touth;
    }

    head_kernel<<<gemm_grid, 256, 0, stream>>>(accbuf, b, w_mu, b_mu, w_ls, b_ls,
                                               (float*)d_out, N);
}

// Round 3
// 1576.765 us; speedup vs baseline: 1.7650x; 1.1929x over previous
//
#include <hip/hip_runtime.h>
#include <hip/hip_fp16.h>

#define N_NODES 50000
#define N_EDGES 800000
#define CH 128
#define OUT_CH 64
#define K_ORD 25
#define SLICE ((size_t)N_NODES * CH)   // elements per T_k slice

typedef __attribute__((ext_vector_type(8))) short s16x8;
typedef __attribute__((ext_vector_type(4))) float f32x4;

union U4H8 { uint4 u; __half2 h2[4]; ushort us[8]; };

// ---------- CSR build ----------
__global__ void count_kernel(const int* __restrict__ ei, float* __restrict__ deg,
                             int* __restrict__ indeg, int E) {
    int e = blockIdx.x * blockDim.x + threadIdx.x;
    if (e >= E) return;
    int s = ei[e];
    int d = ei[E + e];
    atomicAdd(&deg[s], 1.0f);
    atomicAdd(&indeg[d], 1);
}

// parallel scan: per-block exclusive scan + block totals
__global__ __launch_bounds__(256) void scan1_kernel(const int* __restrict__ indeg,
                                                    int* __restrict__ loc,
                                                    int* __restrict__ bsum, int n) {
    __shared__ int tmp[256];
    int tid = threadIdx.x;
    int i = blockIdx.x * 256 + tid;
    int v = (i < n) ? indeg[i] : 0;
    tmp[tid] = v;
    __syncthreads();
    for (int off = 1; off < 256; off <<= 1) {
        int t = (tid >= off) ? tmp[tid - off] : 0;
        __syncthreads();
        tmp[tid] += t;
        __syncthreads();
    }
    if (i < n) loc[i] = tmp[tid] - v;       // exclusive
    if (tid == 255) bsum[blockIdx.x] = tmp[255];
}

__global__ __launch_bounds__(256) void scan2_kernel(int* __restrict__ bsum, int nb) {
    __shared__ int tmp[256];
    int tid = threadIdx.x;
    int v = (tid < nb) ? bsum[tid] : 0;
    tmp[tid] = v;
    __syncthreads();
    for (int off = 1; off < 256; off <<= 1) {
        int t = (tid >= off) ? tmp[tid - off] : 0;
        __syncthreads();
        tmp[tid] += t;
        __syncthreads();
    }
    if (tid < nb) bsum[tid] = tmp[tid] - v; // exclusive
    if (tid == 255) bsum[nb] = tmp[255];    // grand total
}

__global__ __launch_bounds__(256) void scan3_kernel(const int* __restrict__ loc,
                                                    const int* __restrict__ bsum,
                                                    int* __restrict__ rowptr,
                                                    int* __restrict__ cursor, int n, int nb) {
    int i = blockIdx.x * 256 + threadIdx.x;
    if (i < n) {
        int r = loc[i] + bsum[i >> 8];
        rowptr[i] = r;
        cursor[i] = r;
    }
    if (i == n) rowptr[n] = bsum[nb];
}

__global__ void scatter_kernel(const int* __restrict__ ei, const float* __restrict__ deg,
                               int* __restrict__ cursor, int* __restrict__ col,
                               float* __restrict__ ew, int E) {
    int e = blockIdx.x * blockDim.x + threadIdx.x;
    if (e >= E) return;
    int s = ei[e];
    int d = ei[E + e];
    float ds = deg[s], dd = deg[d];
    float dis_s = ds > 0.f ? rsqrtf(ds) : 0.f;
    float dis_d = dd > 0.f ? rsqrtf(dd) : 0.f;
    int pos = atomicAdd(&cursor[d], 1);
    col[pos] = s;
    ew[pos] = -dis_s * dis_d;
}

// ---------- fp32 -> fp16 convert (x -> T0) ----------
__global__ __launch_bounds__(256) void cvt_kernel(const float* __restrict__ in,
                                                  ushort* __restrict__ out, int n8) {
    int i = blockIdx.x * 256 + threadIdx.x;
    if (i >= n8) return;
    float4 a = ((const float4*)in)[2 * i];
    float4 b = ((const float4*)in)[2 * i + 1];
    U4H8 p;
    p.h2[0] = __float22half2_rn(make_float2(a.x, a.y));
    p.h2[1] = __float22half2_rn(make_float2(a.z, a.w));
    p.h2[2] = __float22half2_rn(make_float2(b.x, b.y));
    p.h2[3] = __float22half2_rn(make_float2(b.z, b.w));
    ((uint4*)out)[i] = p.u;
}

// ---------- W prep: WT[k][n][c] = fp16(W[k][c][n]) ----------
__global__ __launch_bounds__(256) void wprep_kernel(const float* __restrict__ W,
                                                    ushort* __restrict__ WT) {
    int idx = blockIdx.x * 256 + threadIdx.x;   // (k, n, c4)
    if (idx >= K_ORD * 128 * 32) return;
    int c4 = idx & 31;
    int nrow = (idx >> 5) & 127;
    int k = idx >> 12;
    const float* Wk = W + (size_t)k * CH * CH;
    ushort o[4];
    #pragma unroll
    for (int j = 0; j < 4; ++j)
        o[j] = __half_as_ushort(__float2half_rn(Wk[(c4 * 4 + j) * CH + nrow]));
    *(ushort2*)(WT + (size_t)k * CH * CH + nrow * CH + c4 * 4)     = make_ushort2(o[0], o[1]);
    *(ushort2*)(WT + (size_t)k * CH * CH + nrow * CH + c4 * 4 + 2) = make_ushort2(o[2], o[3]);
}

// ---------- prop: tout = (mode ? 2*prop(tin) - tprev : prop(tin)), all fp16 ----------
// one wave per node; 4 groups x 16 lanes, each group handles one edge (16B/lane loads)
__global__ __launch_bounds__(256) void prop_kernel(
    const ushort* __restrict__ tin, const ushort* __restrict__ tprev,
    ushort* __restrict__ tout, const int* __restrict__ rowptr,
    const int* __restrict__ col, const float* __restrict__ ew, int n, int mode) {
    int wid = blockIdx.x * 4 + (threadIdx.x >> 6);
    if (wid >= n) return;
    int lane = threadIdx.x & 63;
    int g = lane >> 4, sub = lane & 15;
    int beg = rowptr[wid], end = rowptr[wid + 1];
    float acc[8] = {0.f, 0.f, 0.f, 0.f, 0.f, 0.f, 0.f, 0.f};
    for (int e0 = beg; e0 < end; e0 += 64) {
        int ne = min(64, end - e0);
        int c = 0; float w = 0.f;
        if (lane < ne) { c = col[e0 + lane]; w = ew[e0 + lane]; }
        for (int j4 = 0; j4 < ne; j4 += 4) {
            int j = j4 + g;
            int cj = __shfl(c, j & 63);
            float wj = __shfl(w, j & 63);
            if (j >= ne) wj = 0.f;
            U4H8 v;
            v.u = ((const uint4*)(tin + (size_t)cj * CH))[sub];
            #pragma unroll
            for (int t = 0; t < 4; ++t) {
                float2 f = __half22float2(v.h2[t]);
                acc[2 * t]     = fmaf(wj, f.x, acc[2 * t]);
                acc[2 * t + 1] = fmaf(wj, f.y, acc[2 * t + 1]);
            }
        }
    }
    #pragma unroll
    for (int i = 0; i < 8; ++i) {
        acc[i] += __shfl_xor(acc[i], 16);
        acc[i] += __shfl_xor(acc[i], 32);
    }
    if (g == 0) {
        size_t base = (size_t)wid * CH + sub * 8;
        float r[8];
        if (mode) {
            U4H8 pv;
            pv.u = *(const uint4*)(tprev + base);
            #pragma unroll
            for (int t = 0; t < 4; ++t) {
                float2 f = __half22float2(pv.h2[t]);
                r[2 * t]     = 2.f * acc[2 * t]     - f.x;
                r[2 * t + 1] = 2.f * acc[2 * t + 1] - f.y;
            }
        } else {
            #pragma unroll
            for (int i = 0; i < 8; ++i) r[i] = acc[i];
        }
        U4H8 p;
        p.h2[0] = __float22half2_rn(make_float2(r[0], r[1]));
        p.h2[1] = __float22half2_rn(make_float2(r[2], r[3]));
        p.h2[2] = __float22half2_rn(make_float2(r[4], r[5]));
        p.h2[3] = __float22half2_rn(make_float2(r[6], r[7]));
        *(uint4*)(tout + base) = p.u;
    }
}

// ---------- GEMM: C[M,128] (beta? +=) Σ_{ks} T[k0+ks] @ W[k0+ks], fp16 MFMA ----------
__global__ __launch_bounds__(256) void gemm_kernel(
    const ushort* __restrict__ T, size_t slice_stride, const ushort* __restrict__ WT,
    float* __restrict__ C, int M, int k0, int nk, int beta) {
    __shared__ ushort As[128 * 128];
    __shared__ ushort Ws[128 * 128];
    int tid = threadIdx.x;
    int row0 = blockIdx.x * 128;
    int wave = tid >> 6, lane = tid & 63;
    int wrow = wave * 32;
    int lr = lane & 15, kg = lane >> 4;

    f32x4 acc[2][8];
    #pragma unroll
    for (int a = 0; a < 2; ++a)
        #pragma unroll
        for (int c = 0; c < 8; ++c)
            acc[a][c] = (f32x4){0.f, 0.f, 0.f, 0.f};

    for (int ks = 0; ks < nk; ++ks) {
        const ushort* Ak = T + (size_t)(k0 + ks) * slice_stride;
        const ushort* Wk = WT + (size_t)(k0 + ks) * (CH * CH);
        #pragma unroll
        for (int i = 0; i < 8; ++i) {
            int idx = tid + i * 256;
            int r = idx >> 4, gg = idx & 15;
            uint4 v = make_uint4(0u, 0u, 0u, 0u);
            int gr = row0 + r;
            if (gr < M) v = ((const uint4*)(Ak + (size_t)gr * CH))[gg];
            int gs = gg ^ (r & 15);
            *(uint4*)(&As[r * 128 + gs * 8]) = v;
        }
        #pragma unroll
        for (int i = 0; i < 8; ++i) {
            int idx = tid + i * 256;
            int r = idx >> 4, gg = idx & 15;
            uint4 v = ((const uint4*)(Wk + (size_t)r * CH))[gg];
            int gs = gg ^ (r & 15);
            *(uint4*)(&Ws[r * 128 + gs * 8]) = v;
        }
        __syncthreads();

        #pragma unroll
        for (int kc = 0; kc < 4; ++kc) {
            int gbase = kc * 4 + kg;
            int gs = gbase ^ lr;
            s16x8 a0 = *(const s16x8*)(&As[(wrow + lr) * 128 + gs * 8]);
            s16x8 a1 = *(const s16x8*)(&As[(wrow + 16 + lr) * 128 + gs * 8]);
            #pragma unroll
            for (int c = 0; c < 8; ++c) {
                s16x8 bfr = *(const s16x8*)(&Ws[(c * 16 + lr) * 128 + gs * 8]);
                acc[0][c] = __builtin_amdgcn_mfma_f32_16x16x32_f16(a0, bfr, acc[0][c], 0, 0, 0);
                acc[1][c] = __builtin_amdgcn_mfma_f32_16x16x32_f16(a1, bfr, acc[1][c], 0, 0, 0);
            }
        }
        __syncthreads();
    }

    #pragma unroll
    for (int rf = 0; rf < 2; ++rf)
        #pragma unroll
        for (int c = 0; c < 8; ++c)
            #pragma unroll
            for (int j = 0; j < 4; ++j) {
                int gr = row0 + wrow + rf * 16 + kg * 4 + j;
                int gc = c * 16 + lr;
                if (gr < M) {
                    float v = acc[rf][c][j];
                    if (beta) v += C[(size_t)gr * 128 + gc];
                    C[(size_t)gr * 128 + gc] = v;
                }
            }
}

// ---------- head: MFMA over Wcat = [w_mu | w_ls], fused leaky+bias+normalize ----------
__global__ __launch_bounds__(256) void head_kernel(
    const float* __restrict__ acc_in, const float* __restrict__ b,
    const float* __restrict__ w_mu, const float* __restrict__ b_mu,
    const float* __restrict__ w_ls, const float* __restrict__ b_ls,
    float* __restrict__ out, int M) {
    __shared__ ushort Hs[128 * 128];
    __shared__ ushort Ws[128 * 128];
    __shared__ float s_b[128];
    int tid = threadIdx.x;
    int row0 = blockIdx.x * 128;
    if (tid < 128) s_b[tid] = b[tid];
    __syncthreads();

    #pragma unroll
    for (int i = 0; i < 16; ++i) {
        int idx = tid + i * 256;
        int r = idx >> 5, c4 = idx & 31;
        float4 v = make_float4(0.f, 0.f, 0.f, 0.f);
        int gr = row0 + r;
        if (gr < M) v = ((const float4*)(acc_in + (size_t)gr * CH))[c4];
        float hv[4] = { v.x, v.y, v.z, v.w };
        #pragma unroll
        for (int j = 0; j < 4; ++j) {
            float h = hv[j] + s_b[c4 * 4 + j];
            hv[j] = h > 0.f ? h : 0.01f * h;
        }
        __half2 p0 = __float22half2_rn(make_float2(hv[0], hv[1]));
        __half2 p1 = __float22half2_rn(make_float2(hv[2], hv[3]));
        int gg = c4 >> 1, hh = c4 & 1;
        int gs = gg ^ (r & 15);
        uint2 pk;
        pk.x = *(unsigned int*)&p0;
        pk.y = *(unsigned int*)&p1;
        *(uint2*)(&Hs[r * 128 + gs * 8 + hh * 4]) = pk;
    }
    #pragma unroll
    for (int i = 0; i < 16; ++i) {
        int idx = tid + i * 256;
        int k = idx >> 5, n4 = idx & 31;
        const float* src = (n4 < 16) ? w_mu : w_ls;
        float4 v = ((const float4*)src)[k * 16 + (n4 & 15)];
        int gk = k >> 3, kk = k & 7;
        float vv[4] = { v.x, v.y, v.z, v.w };
        #pragma unroll
        for (int j = 0; j < 4; ++j) {
            int nn = n4 * 4 + j;
            int gs = gk ^ (nn & 15);
            Ws[nn * 128 + gs * 8 + kk] = __half_as_ushort(__float2half_rn(vv[j]));
        }
    }
    __syncthreads();

    int wave = tid >> 6, lane = tid & 63;
    int wrow = wave * 32;
    int lr = lane & 15, kg = lane >> 4;
    f32x4 acc[2][8];
    #pragma unroll
    for (int a = 0; a < 2; ++a)
        #pragma unroll
        for (int c = 0; c < 8; ++c)
            acc[a][c] = (f32x4){0.f, 0.f, 0.f, 0.f};

    #pragma unroll
    for (int kc = 0; kc < 4; ++kc) {
        int gbase = kc * 4 + kg;
        int gs = gbase ^ lr;
        s16x8 a0 = *(const s16x8*)(&Hs[(wrow + lr) * 128 + gs * 8]);
        s16x8 a1 = *(const s16x8*)(&Hs[(wrow + 16 + lr) * 128 + gs * 8]);
        #pragma unroll
        for (int c = 0; c < 8; ++c) {
            s16x8 bfr = *(const s16x8*)(&Ws[(c * 16 + lr) * 128 + gs * 8]);
            acc[0][c] = __builtin_amdgcn_mfma_f32_16x16x32_f16(a0, bfr, acc[0][c], 0, 0, 0);
            acc[1][c] = __builtin_amdgcn_mfma_f32_16x16x32_f16(a1, bfr, acc[1][c], 0, 0, 0);
        }
    }

    #pragma unroll
    for (int rf = 0; rf < 2; ++rf)
        #pragma unroll
        for (int j = 0; j < 4; ++j) {
            int gr = row0 + wrow + rf * 16 + kg * 4 + j;
            float muv[4], lsv[4];
            float s2 = 0.f;
            #pragma unroll
            for (int c = 0; c < 4; ++c) {
                muv[c] = acc[rf][c][j] + b_mu[c * 16 + lr];
                float l = acc[rf][4 + c][j] + b_ls[c * 16 + lr];
                lsv[c] = l;
                s2 = fmaf(l, l, s2);
            }
            s2 += __shfl_xor(s2, 1);
            s2 += __shfl_xor(s2, 2);
            s2 += __shfl_xor(s2, 4);
            s2 += __shfl_xor(s2, 8);
            float sc = 1.8f / fmaxf(sqrtf(s2), 1e-12f);
            if (gr < M) {
                size_t base = (size_t)gr * OUT_CH;
                #pragma unroll
                for (int c = 0; c < 4; ++c) {
                    int gc = c * 16 + lr;
                    out[base + gc] = muv[c];
                    out[(size_t)N_NODES * OUT_CH + base + gc] = lsv[c] * sc;
                    out[2 * (size_t)N_NODES * OUT_CH + base + gc] = muv[c];
                }
            }
        }
}

// ---------- host ----------
extern "C" void kernel_launch(void* const* d_in, const int* in_sizes, int n_in,
                              void* d_out, int out_size, void* d_ws, size_t ws_size,
                              hipStream_t stream) {
    const float* x    = (const float*)d_in[0];
    const int*   ei   = (const int*)d_in[1];
    const float* W    = (const float*)d_in[2];
    const float* b    = (const float*)d_in[3];
    const float* w_mu = (const float*)d_in[4];
    const float* b_mu = (const float*)d_in[5];
    const float* w_ls = (const float*)d_in[6];
    const float* b_ls = (const float*)d_in[7];

    const int N = N_NODES, E = N_EDGES;
    const int NB = (N + 255) / 256;   // 196 scan blocks
    char* p = (char*)d_ws;
    auto alloc = [&](size_t bytes) {
        char* r = p;
        p += (bytes + 511) & ~(size_t)511;
        return r;
    };
    float*  deg    = (float*)alloc((size_t)N * 4);
    int*    indeg  = (int*)alloc((size_t)N * 4);
    int*    rowptr = (int*)alloc((size_t)(N + 1) * 4);
    int*    cursor = (int*)alloc((size_t)N * 4);
    int*    loc    = (int*)alloc((size_t)N * 4);
    int*    bsum   = (int*)alloc((size_t)(NB + 1) * 4);
    int*    col    = (int*)alloc((size_t)E * 4);
    float*  ew     = (float*)alloc((size_t)E * 4);
    ushort* WT     = (ushort*)alloc((size_t)K_ORD * CH * CH * 2);
    float*  accbuf = (float*)alloc((size_t)N * CH * 4);

    size_t used_common = (size_t)(p - (char*)d_ws);
    size_t tbuf_bytes  = (size_t)K_ORD * SLICE * 2;
    bool bigpath = ws_size >= used_common + tbuf_bytes + (1u << 20);

    hipMemsetAsync(deg, 0, (size_t)N * 4, stream);
    hipMemsetAsync(indeg, 0, (size_t)N * 4, stream);

    count_kernel<<<(E + 255) / 256, 256, 0, stream>>>(ei, deg, indeg, E);
    scan1_kernel<<<NB, 256, 0, stream>>>(indeg, loc, bsum, N);
    scan2_kernel<<<1, 256, 0, stream>>>(bsum, NB);
    scan3_kernel<<<NB, 256, 0, stream>>>(loc, bsum, rowptr, cursor, N, NB);
    scatter_kernel<<<(E + 255) / 256, 256, 0, stream>>>(ei, deg, cursor, col, ew, E);
    wprep_kernel<<<(K_ORD * 128 * 32 + 255) / 256, 256, 0, stream>>>(W, WT);

    int gemm_grid = (N + 127) / 128;
    int prop_grid = (N + 3) / 4;

    if (bigpath) {
        ushort* Tbuf = (ushort*)alloc(tbuf_bytes);
        // T0 = fp16(x)
        cvt_kernel<<<(N * CH / 8 + 255) / 256, 256, 0, stream>>>(x, Tbuf, N * CH / 8);
        // T1 = prop(T0)
        prop_kernel<<<prop_grid, 256, 0, stream>>>(Tbuf, Tbuf, Tbuf + SLICE,
                                                   rowptr, col, ew, N, 0);
        // Tk = 2*prop(T_{k-1}) - T_{k-2}
        for (int k = 2; k < K_ORD; ++k)
            prop_kernel<<<prop_grid, 256, 0, stream>>>(
                Tbuf + (size_t)(k - 1) * SLICE, Tbuf + (size_t)(k - 2) * SLICE,
                Tbuf + (size_t)k * SLICE, rowptr, col, ew, N, 1);
        // acc = sum_k T_k @ W_k  (single K=3200 GEMM)
        gemm_kernel<<<gemm_grid, 256, 0, stream>>>(Tbuf, SLICE, WT, accbuf, N, 0, K_ORD, 0);
    } else {
        ushort* r0 = (ushort*)alloc(SLICE * 2);
        ushort* r1 = (ushort*)alloc(SLICE * 2);
        ushort* r2 = (ushort*)alloc(SLICE * 2);
        cvt_kernel<<<(N * CH / 8 + 255) / 256, 256, 0, stream>>>(x, r0, N * CH / 8);
        gemm_kernel<<<gemm_grid, 256, 0, stream>>>(r0, 0, WT, accbuf, N, 0, 1, 0);
        prop_kernel<<<prop_grid, 256, 0, stream>>>(r0, r0, r1, rowptr, col, ew, N, 0);
        gemm_kernel<<<gemm_grid, 256, 0, stream>>>(r1, 0, WT, accbuf, N, 1, 1, 1);
        ushort* tm2 = r0;
        ushort* tm1 = r1;
        ushort* tnx = r2;
        for (int k = 2; k < K_ORD; ++k) {
            prop_kernel<<<prop_grid, 256, 0, stream>>>(tm1, tm2, tnx, rowptr, col, ew, N, 1);
            gemm_kernel<<<gemm_grid, 256, 0, stream>>>(tnx, 0, WT, accbuf, N, k, 1, 1);
            ushort* t = tm2; tm2 = tm1; tm1 = tnx; tnx = t;
        }
    }

    head_kernel<<<gemm_grid, 256, 0, stream>>>(accbuf, b, w_mu, b_mu, w_ls, b_ls,
                                               (float*)d_out, N);
}